// Round 2
// baseline (412.151 us; speedup 1.0000x reference)
//
#include <hip/hip_runtime.h>
#include <hip/hip_bf16.h>

#define N 8192
#define D 128
#define LOG2E  1.44269504088896f
#define MLOG2E 0.14426950408890f   // MARGIN * log2e, MARGIN = 0.1
#define LN2    0.69314718055995f

typedef __attribute__((ext_vector_type(8))) short bf16x8;
typedef __attribute__((ext_vector_type(4))) float f32x4;

#if __has_builtin(__builtin_amdgcn_exp2f)
#define EXP2(x) __builtin_amdgcn_exp2f(x)
#else
#define EXP2(x) exp2f(x)
#endif
#if __has_builtin(__builtin_amdgcn_logf)
#define LOG2(x) __builtin_amdgcn_logf(x)
#else
#define LOG2(x) log2f(x)
#endif

static __device__ __forceinline__ unsigned short f2bf(float f) {
    union { float f; unsigned int u; } x;
    x.f = f;
    unsigned int r = ((x.u >> 16) & 1u) + 0x7FFFu;  // round-to-nearest-even
    return (unsigned short)((x.u + r) >> 16);
}

// Kernel 1: E (fp32) -> bf16 in ws; zero rowsum accumulator and out[0].
__global__ void prep_kernel(const float* __restrict__ E,
                            unsigned short* __restrict__ Eb,
                            float* __restrict__ rowsum,
                            float* __restrict__ out) {
    int idx = blockIdx.x * 256 + threadIdx.x;   // 262144 threads, 4 elems each
    float4 v = ((const float4*)E)[idx];
    ushort4 o;
    o.x = f2bf(v.x); o.y = f2bf(v.y); o.z = f2bf(v.z); o.w = f2bf(v.w);
    ((ushort4*)Eb)[idx] = o;
    if (idx < N) rowsum[idx] = 0.0f;
    if (idx == 0) out[0] = 0.0f;
}

// Kernel 2: fused sim = E*E^T -> exp(+/-(sim - margin)) -> row sums.
// 1024 blocks x 4 waves = 4096 waves. chunk = blockIdx&31 (256 cols),
// strip = (blockIdx>>5)*4 + waveid (64 rows). 16 t-iters of 16 cols,
// with explicit next-tile prefetch of B-frags + labels.
__global__ __launch_bounds__(256, 4) void fused_kernel(
        const unsigned short* __restrict__ Eb,
        const int* __restrict__ labels,
        float* __restrict__ rowsum) {
    const int wid   = threadIdx.x >> 6;
    const int lane  = threadIdx.x & 63;
    const int chunk = blockIdx.x & 31;                 // 0..31 -> 256-col span
    const int strip = ((blockIdx.x >> 5) << 2) + wid;  // 0..127 -> 64-row span
    const int m0 = strip * 64;
    const int n_begin = chunk * 256;
    const int q = lane >> 4;       // 0..3
    const int l = lane & 15;       // 0..15

    // A fragments: a[g][kk] = E[m0+g*16+l][kk*32 + q*8 .. +7]
    bf16x8 a[4][4];
#pragma unroll
    for (int g = 0; g < 4; ++g) {
        const bf16x8* p = (const bf16x8*)(Eb + (size_t)(m0 + g * 16 + l) * D + q * 8);
#pragma unroll
        for (int kk = 0; kk < 4; ++kk) a[g][kk] = p[kk * 4];
    }

    // Row labels for the 16 output rows this lane owns (row = g*16 + q*4 + r).
    int lrow[16];
#pragma unroll
    for (int g = 0; g < 4; ++g)
#pragma unroll
        for (int r = 0; r < 4; ++r)
            lrow[g * 4 + r] = labels[m0 + g * 16 + q * 4 + r];

    float sum[16];
#pragma unroll
    for (int i = 0; i < 16; ++i) sum[i] = 0.0f;

    int colc = n_begin + l;
    const bf16x8* bp = (const bf16x8*)(Eb + (size_t)colc * D + q * 8);
    bf16x8 b0 = bp[0], b1 = bp[4], b2 = bp[8], b3 = bp[12];
    int lc = labels[colc];

    for (int t = 0; t < 16; ++t) {
        // prefetch next 16-col tile
        bf16x8 p0, p1, p2, p3; int lcn = 0;
        if (t < 15) {
            const bf16x8* np = (const bf16x8*)(Eb + (size_t)(colc + 16) * D + q * 8);
            p0 = np[0]; p1 = np[4]; p2 = np[8]; p3 = np[12];
            lcn = labels[colc + 16];
        }

        f32x4 acc[4];
#pragma unroll
        for (int g = 0; g < 4; ++g) {
            acc[g] = (f32x4){0.f, 0.f, 0.f, 0.f};
            acc[g] = __builtin_amdgcn_mfma_f32_16x16x32_bf16(a[g][0], b0, acc[g], 0, 0, 0);
            acc[g] = __builtin_amdgcn_mfma_f32_16x16x32_bf16(a[g][1], b1, acc[g], 0, 0, 0);
            acc[g] = __builtin_amdgcn_mfma_f32_16x16x32_bf16(a[g][2], b2, acc[g], 0, 0, 0);
            acc[g] = __builtin_amdgcn_mfma_f32_16x16x32_bf16(a[g][3], b3, acc[g], 0, 0, 0);
        }

#pragma unroll
        for (int g = 0; g < 4; ++g) {
#pragma unroll
            for (int r = 0; r < 4; ++r) {
                float s = acc[g][r];
                bool eq = (lrow[g * 4 + r] == lc);
                float c = eq ? -LOG2E : LOG2E;
                float d = eq ? MLOG2E : -MLOG2E;
                sum[g * 4 + r] += EXP2(fmaf(s, c, d));
            }
        }

        if (t < 15) { b0 = p0; b1 = p1; b2 = p2; b3 = p3; lc = lcn; colc += 16; }
    }

    // Reduce across the 16 column-lanes (xor masks keep q fixed).
#pragma unroll
    for (int i = 0; i < 16; ++i) {
        float v = sum[i];
        v += __shfl_xor(v, 1);
        v += __shfl_xor(v, 2);
        v += __shfl_xor(v, 4);
        v += __shfl_xor(v, 8);
        sum[i] = v;
    }
    if (l == 0) {
#pragma unroll
        for (int g = 0; g < 4; ++g)
#pragma unroll
            for (int r = 0; r < 4; ++r)
                atomicAdd(&rowsum[m0 + g * 16 + q * 4 + r], sum[g * 4 + r]);
    }
}

// Kernel 3: out += sum_i log(rowsum[i]) / N, 32 blocks of 256.
__global__ void finalize_kernel(const float* __restrict__ rowsum, float* __restrict__ out) {
    __shared__ float red[4];
    int i = blockIdx.x * 256 + threadIdx.x;
    float v = LOG2(rowsum[i]) * LN2;
#pragma unroll
    for (int off = 1; off <= 32; off <<= 1) v += __shfl_xor(v, off);
    if ((threadIdx.x & 63) == 0) red[threadIdx.x >> 6] = v;
    __syncthreads();
    if (threadIdx.x == 0)
        atomicAdd(out, (red[0] + red[1] + red[2] + red[3]) * (1.0f / (float)N));
}

extern "C" void kernel_launch(void* const* d_in, const int* in_sizes, int n_in,
                              void* d_out, int out_size, void* d_ws, size_t ws_size,
                              hipStream_t stream) {
    const float* E = (const float*)d_in[0];
    const int* labels = (const int*)d_in[1];
    float* out = (float*)d_out;

    unsigned short* Eb = (unsigned short*)d_ws;                                    // 2 MiB
    float* rowsum = (float*)((char*)d_ws + (size_t)N * D * sizeof(unsigned short)); // 32 KiB

    prep_kernel<<<1024, 256, 0, stream>>>(E, Eb, rowsum, out);
    fused_kernel<<<1024, 256, 0, stream>>>(Eb, labels, rowsum);
    finalize_kernel<<<32, 256, 0, stream>>>(rowsum, out);
}

// Round 3
// 182.446 us; speedup vs baseline: 2.2590x; 2.2590x over previous
//
#include <hip/hip_runtime.h>
#include <hip/hip_bf16.h>

#define N 8192
#define D 128
#define LOG2E  1.44269504088896f
#define MLOG2E 0.14426950408890f   // MARGIN * log2e, MARGIN = 0.1
#define LN2    0.69314718055995f

typedef __attribute__((ext_vector_type(8))) short bf16x8;
typedef __attribute__((ext_vector_type(4))) float f32x4;

#if __has_builtin(__builtin_amdgcn_exp2f)
#define EXP2(x) __builtin_amdgcn_exp2f(x)
#else
#define EXP2(x) exp2f(x)
#endif
#if __has_builtin(__builtin_amdgcn_logf)
#define LOG2(x) __builtin_amdgcn_logf(x)
#else
#define LOG2(x) log2f(x)
#endif

static __device__ __forceinline__ unsigned short f2bf(float f) {
    union { float f; unsigned int u; } x;
    x.f = f;
    unsigned int r = ((x.u >> 16) & 1u) + 0x7FFFu;  // round-to-nearest-even
    return (unsigned short)((x.u + r) >> 16);
}

// Kernel 1: E (fp32) -> bf16 in ws; zero rowsum accumulator + ticket counter.
__global__ void prep_kernel(const float* __restrict__ E,
                            unsigned short* __restrict__ Eb,
                            float* __restrict__ rowsum,
                            unsigned int* __restrict__ counter) {
    int idx = blockIdx.x * 256 + threadIdx.x;   // 262144 threads, 4 elems each
    float4 v = ((const float4*)E)[idx];
    ushort4 o;
    o.x = f2bf(v.x); o.y = f2bf(v.y); o.z = f2bf(v.z); o.w = f2bf(v.w);
    ((ushort4*)Eb)[idx] = o;
    if (idx < N) rowsum[idx] = 0.0f;
    if (idx == 0) *counter = 0u;
}

// Kernel 2: fused sim = E*E^T -> exp(+/-(sim - margin)) -> row sums -> (last
// block) loss = mean log(rowsum).
// 1024 blocks x 4 waves = 4096 waves. chunk = blockIdx&31 (256 cols),
// strip = (blockIdx>>5)*4 + wid (64 rows). NO min-wave launch_bounds:
// round-2's (256,4) forced VGPR 64 and spilled A-frags to scratch
// (FETCH 5MB->396MB, 351us). Round-1 body (76 VGPR) + bigger grid instead.
__global__ __launch_bounds__(256) void fused_kernel(
        const unsigned short* __restrict__ Eb,
        const int* __restrict__ labels,
        float* __restrict__ rowsum,
        unsigned int* __restrict__ counter,
        float* __restrict__ out) {
    const int wid   = threadIdx.x >> 6;
    const int lane  = threadIdx.x & 63;
    const int chunk = blockIdx.x & 31;                 // 256-col span
    const int strip = ((blockIdx.x >> 5) << 2) + wid;  // 64-row span
    const int m0 = strip * 64;
    const int n_begin = chunk * 256;
    const int q = lane >> 4;       // 0..3
    const int l = lane & 15;       // 0..15

    // A fragments: a[g][kk] = E[m0+g*16+l][kk*32 + q*8 .. +7]
    bf16x8 a[4][4];
#pragma unroll
    for (int g = 0; g < 4; ++g) {
        const bf16x8* p = (const bf16x8*)(Eb + (size_t)(m0 + g * 16 + l) * D + q * 8);
#pragma unroll
        for (int kk = 0; kk < 4; ++kk) a[g][kk] = p[kk * 4];
    }

    // Row labels for the 16 output rows this lane owns (row = g*16 + q*4 + r).
    int lrow[16];
#pragma unroll
    for (int g = 0; g < 4; ++g)
#pragma unroll
        for (int r = 0; r < 4; ++r)
            lrow[g * 4 + r] = labels[m0 + g * 16 + q * 4 + r];

    float sum[16];
#pragma unroll
    for (int i = 0; i < 16; ++i) sum[i] = 0.0f;

    for (int t = 0; t < 16; ++t) {
        const int col = n_begin + t * 16 + l;
        const int lc = labels[col];
        const bf16x8* bp = (const bf16x8*)(Eb + (size_t)col * D + q * 8);
        bf16x8 b0 = bp[0], b1 = bp[4], b2 = bp[8], b3 = bp[12];

        f32x4 acc[4];
#pragma unroll
        for (int g = 0; g < 4; ++g) {
            acc[g] = (f32x4){0.f, 0.f, 0.f, 0.f};
            acc[g] = __builtin_amdgcn_mfma_f32_16x16x32_bf16(a[g][0], b0, acc[g], 0, 0, 0);
            acc[g] = __builtin_amdgcn_mfma_f32_16x16x32_bf16(a[g][1], b1, acc[g], 0, 0, 0);
            acc[g] = __builtin_amdgcn_mfma_f32_16x16x32_bf16(a[g][2], b2, acc[g], 0, 0, 0);
            acc[g] = __builtin_amdgcn_mfma_f32_16x16x32_bf16(a[g][3], b3, acc[g], 0, 0, 0);
        }

#pragma unroll
        for (int g = 0; g < 4; ++g) {
#pragma unroll
            for (int r = 0; r < 4; ++r) {
                float s = acc[g][r];
                bool eq = (lrow[g * 4 + r] == lc);
                float c = eq ? -LOG2E : LOG2E;
                float d = eq ? MLOG2E : -MLOG2E;
                sum[g * 4 + r] += EXP2(fmaf(s, c, d));
            }
        }
    }

    // Reduce across the 16 column-lanes (xor masks keep q fixed).
#pragma unroll
    for (int i = 0; i < 16; ++i) {
        float v = sum[i];
        v += __shfl_xor(v, 1);
        v += __shfl_xor(v, 2);
        v += __shfl_xor(v, 4);
        v += __shfl_xor(v, 8);
        sum[i] = v;
    }
    if (l == 0) {
#pragma unroll
        for (int g = 0; g < 4; ++g)
#pragma unroll
            for (int r = 0; r < 4; ++r)
                atomicAdd(&rowsum[m0 + g * 16 + q * 4 + r], sum[g * 4 + r]);
    }

    // ---- ticket: last block to finish computes the final loss ----
    __shared__ unsigned int ticket;
    __shared__ float red[4];
    __threadfence();            // make this thread's rowsum atomics visible
    __syncthreads();            // all threads in block done
    if (threadIdx.x == 0) ticket = atomicAdd(counter, 1u);
    __syncthreads();
    if (ticket == 1023u) {
        __threadfence();        // acquire
        float s = 0.0f;
        for (int i = threadIdx.x; i < N; i += 256) {
            float rv = __hip_atomic_load(&rowsum[i], __ATOMIC_RELAXED,
                                         __HIP_MEMORY_SCOPE_AGENT);
            s += LOG2(rv);
        }
        s *= LN2;
#pragma unroll
        for (int off = 1; off <= 32; off <<= 1) s += __shfl_xor(s, off);
        if (lane == 0) red[wid] = s;
        __syncthreads();
        if (threadIdx.x == 0)
            out[0] = (red[0] + red[1] + red[2] + red[3]) * (1.0f / (float)N);
    }
}

extern "C" void kernel_launch(void* const* d_in, const int* in_sizes, int n_in,
                              void* d_out, int out_size, void* d_ws, size_t ws_size,
                              hipStream_t stream) {
    const float* E = (const float*)d_in[0];
    const int* labels = (const int*)d_in[1];
    float* out = (float*)d_out;

    unsigned short* Eb = (unsigned short*)d_ws;                                     // 2 MiB
    float* rowsum = (float*)((char*)d_ws + (size_t)N * D * sizeof(unsigned short)); // 32 KiB
    unsigned int* counter = (unsigned int*)(rowsum + N);                            // 4 B

    prep_kernel<<<1024, 256, 0, stream>>>(E, Eb, rowsum, counter);
    fused_kernel<<<1024, 256, 0, stream>>>(Eb, labels, rowsum, counter, out);
}

// Round 4
// 126.504 us; speedup vs baseline: 3.2580x; 1.4422x over previous
//
#include <hip/hip_runtime.h>
#include <hip/hip_bf16.h>

#define N 8192
#define D 128
#define LOG2E  1.44269504088896f
#define MLOG2E 0.14426950408890f   // MARGIN * log2e, MARGIN = 0.1
#define LN2    0.69314718055995f

typedef __attribute__((ext_vector_type(8))) short bf16x8;
typedef __attribute__((ext_vector_type(4))) float f32x4;

#if __has_builtin(__builtin_amdgcn_exp2f)
#define EXP2(x) __builtin_amdgcn_exp2f(x)
#else
#define EXP2(x) exp2f(x)
#endif
#if __has_builtin(__builtin_amdgcn_logf)
#define LOG2(x) __builtin_amdgcn_logf(x)
#else
#define LOG2(x) log2f(x)
#endif

static __device__ __forceinline__ unsigned short f2bf(float f) {
    union { float f; unsigned int u; } x;
    x.f = f;
    unsigned int r = ((x.u >> 16) & 1u) + 0x7FFFu;  // round-to-nearest-even
    return (unsigned short)((x.u + r) >> 16);
}

// Kernel 1: E (fp32) -> bf16 in ws; zero rowsum accumulator and out[0].
__global__ void prep_kernel(const float* __restrict__ E,
                            unsigned short* __restrict__ Eb,
                            float* __restrict__ rowsum,
                            float* __restrict__ out) {
    int idx = blockIdx.x * 256 + threadIdx.x;   // 262144 threads, 4 elems each
    float4 v = ((const float4*)E)[idx];
    ushort4 o;
    o.x = f2bf(v.x); o.y = f2bf(v.y); o.z = f2bf(v.z); o.w = f2bf(v.w);
    ((ushort4*)Eb)[idx] = o;
    if (idx < N) rowsum[idx] = 0.0f;
    if (idx == 0) out[0] = 0.0f;
}

// Kernel 2: fused sim = E*E^T -> exp(+/-(sim - margin)) -> row sums.
// 1024 blocks x 4 waves. chunk = blockIdx&31 (256 cols),
// strip = (blockIdx>>5)*4 + wid (64 rows).
// NOTE (R2/R3 lessons): no min-waves launch_bounds (spills at VGPR<=112);
// no fused epilogue (allocator balloons to 256 VGPR + scratch spill).
// This body compiles to 76 VGPR -> 6 waves/SIMD; 1024 blocks = 4 blocks/CU
// co-resident (16 waves/CU) for latency hiding.
__global__ __launch_bounds__(256) void fused_kernel(
        const unsigned short* __restrict__ Eb,
        const int* __restrict__ labels,
        float* __restrict__ rowsum) {
    const int wid   = threadIdx.x >> 6;
    const int lane  = threadIdx.x & 63;
    const int chunk = blockIdx.x & 31;                 // 256-col span
    const int strip = ((blockIdx.x >> 5) << 2) + wid;  // 64-row span
    const int m0 = strip * 64;
    const int n_begin = chunk * 256;
    const int q = lane >> 4;       // 0..3
    const int l = lane & 15;       // 0..15

    // A fragments: a[g][kk] = E[m0+g*16+l][kk*32 + q*8 .. +7]
    bf16x8 a[4][4];
#pragma unroll
    for (int g = 0; g < 4; ++g) {
        const bf16x8* p = (const bf16x8*)(Eb + (size_t)(m0 + g * 16 + l) * D + q * 8);
#pragma unroll
        for (int kk = 0; kk < 4; ++kk) a[g][kk] = p[kk * 4];
    }

    // Row labels for the 16 output rows this lane owns (row = g*16 + q*4 + r).
    int lrow[16];
#pragma unroll
    for (int g = 0; g < 4; ++g)
#pragma unroll
        for (int r = 0; r < 4; ++r)
            lrow[g * 4 + r] = labels[m0 + g * 16 + q * 4 + r];

    float sum[16];
#pragma unroll
    for (int i = 0; i < 16; ++i) sum[i] = 0.0f;

    for (int t = 0; t < 16; ++t) {
        const int col = n_begin + t * 16 + l;
        const int lc = labels[col];
        const bf16x8* bp = (const bf16x8*)(Eb + (size_t)col * D + q * 8);
        bf16x8 b0 = bp[0], b1 = bp[4], b2 = bp[8], b3 = bp[12];

        f32x4 acc[4];
#pragma unroll
        for (int g = 0; g < 4; ++g) {
            acc[g] = (f32x4){0.f, 0.f, 0.f, 0.f};
            acc[g] = __builtin_amdgcn_mfma_f32_16x16x32_bf16(a[g][0], b0, acc[g], 0, 0, 0);
            acc[g] = __builtin_amdgcn_mfma_f32_16x16x32_bf16(a[g][1], b1, acc[g], 0, 0, 0);
            acc[g] = __builtin_amdgcn_mfma_f32_16x16x32_bf16(a[g][2], b2, acc[g], 0, 0, 0);
            acc[g] = __builtin_amdgcn_mfma_f32_16x16x32_bf16(a[g][3], b3, acc[g], 0, 0, 0);
        }

#pragma unroll
        for (int g = 0; g < 4; ++g) {
#pragma unroll
            for (int r = 0; r < 4; ++r) {
                float s = acc[g][r];
                bool eq = (lrow[g * 4 + r] == lc);
                float c = eq ? -LOG2E : LOG2E;
                float d = eq ? MLOG2E : -MLOG2E;
                sum[g * 4 + r] += EXP2(fmaf(s, c, d));
            }
        }
    }

    // Reduce across the 16 column-lanes (xor masks keep q fixed).
#pragma unroll
    for (int i = 0; i < 16; ++i) {
        float v = sum[i];
        v += __shfl_xor(v, 1);
        v += __shfl_xor(v, 2);
        v += __shfl_xor(v, 4);
        v += __shfl_xor(v, 8);
        sum[i] = v;
    }
    if (l == 0) {
#pragma unroll
        for (int g = 0; g < 4; ++g)
#pragma unroll
            for (int r = 0; r < 4; ++r)
                atomicAdd(&rowsum[m0 + g * 16 + q * 4 + r], sum[g * 4 + r]);
    }
}

// Kernel 3: out += sum_i log(rowsum[i]) / N, 32 blocks of 256.
__global__ void finalize_kernel(const float* __restrict__ rowsum, float* __restrict__ out) {
    __shared__ float red[4];
    int i = blockIdx.x * 256 + threadIdx.x;
    float v = LOG2(rowsum[i]) * LN2;
#pragma unroll
    for (int off = 1; off <= 32; off <<= 1) v += __shfl_xor(v, off);
    if ((threadIdx.x & 63) == 0) red[threadIdx.x >> 6] = v;
    __syncthreads();
    if (threadIdx.x == 0)
        atomicAdd(out, (red[0] + red[1] + red[2] + red[3]) * (1.0f / (float)N));
}

extern "C" void kernel_launch(void* const* d_in, const int* in_sizes, int n_in,
                              void* d_out, int out_size, void* d_ws, size_t ws_size,
                              hipStream_t stream) {
    const float* E = (const float*)d_in[0];
    const int* labels = (const int*)d_in[1];
    float* out = (float*)d_out;

    unsigned short* Eb = (unsigned short*)d_ws;                                     // 2 MiB
    float* rowsum = (float*)((char*)d_ws + (size_t)N * D * sizeof(unsigned short)); // 32 KiB

    prep_kernel<<<1024, 256, 0, stream>>>(E, Eb, rowsum, out);
    fused_kernel<<<1024, 256, 0, stream>>>(Eb, labels, rowsum);
    finalize_kernel<<<32, 256, 0, stream>>>(rowsum, out);
}

// Round 5
// 109.426 us; speedup vs baseline: 3.7665x; 1.1561x over previous
//
#include <hip/hip_runtime.h>
#include <hip/hip_bf16.h>

#define N 8192
#define D 128
#define LOG2E  1.44269504088896f
#define MLOG2E 0.14426950408890f   // MARGIN * log2e, MARGIN = 0.1
#define LN2    0.69314718055995f

typedef __attribute__((ext_vector_type(8))) short bf16x8;
typedef __attribute__((ext_vector_type(4))) float f32x4;

#if __has_builtin(__builtin_amdgcn_exp2f)
#define EXP2(x) __builtin_amdgcn_exp2f(x)
#else
#define EXP2(x) exp2f(x)
#endif
#if __has_builtin(__builtin_amdgcn_logf)
#define LOG2(x) __builtin_amdgcn_logf(x)
#else
#define LOG2(x) log2f(x)
#endif

static __device__ __forceinline__ unsigned short f2bf(float f) {
    union { float f; unsigned int u; } x;
    x.f = f;
    unsigned int r = ((x.u >> 16) & 1u) + 0x7FFFu;  // round-to-nearest-even
    return (unsigned short)((x.u + r) >> 16);
}

// Kernel 1: E (fp32) -> bf16 in ws; zero rowsum accumulator and out[0].
__global__ void prep_kernel(const float* __restrict__ E,
                            unsigned short* __restrict__ Eb,
                            float* __restrict__ rowsum,
                            float* __restrict__ out) {
    int idx = blockIdx.x * 256 + threadIdx.x;   // 262144 threads, 4 elems each
    float4 v = ((const float4*)E)[idx];
    ushort4 o;
    o.x = f2bf(v.x); o.y = f2bf(v.y); o.z = f2bf(v.z); o.w = f2bf(v.w);
    ((ushort4*)Eb)[idx] = o;
    if (idx < N) rowsum[idx] = 0.0f;
    if (idx == 0) out[0] = 0.0f;
}

// Kernel 2: fused sim = E*E^T -> exp(+/-(sim - margin)) -> row sums.
// 1024 blocks x 4 waves. chunk = blockIdx&31 (256 cols),
// strip = (blockIdx>>5)*4 + wid (64 rows).
// VGPR history (controls everything): 76 -> 48.7us @18% occ (R1, 32-trip
// loop); 216 -> 70us @10% occ (R4 -- compiler FULLY UNROLLED the 16-trip
// loop); 256+spill -> 130us (R3 fused epilogue); 64+forced spill -> 351us
// (R2 launch_bounds(256,4)). Fix: forbid unrolling of the t-loop so the
// allocator finds the compact ~76-VGPR solution; occupancy then comes from
// the 1024-block grid (4 blocks/CU, 16 waves/CU).
__global__ __launch_bounds__(256) void fused_kernel(
        const unsigned short* __restrict__ Eb,
        const int* __restrict__ labels,
        float* __restrict__ rowsum) {
    const int wid   = threadIdx.x >> 6;
    const int lane  = threadIdx.x & 63;
    const int chunk = blockIdx.x & 31;                 // 256-col span
    const int strip = ((blockIdx.x >> 5) << 2) + wid;  // 64-row span
    const int m0 = strip * 64;
    const int n_begin = chunk * 256;
    const int q = lane >> 4;       // 0..3
    const int l = lane & 15;       // 0..15

    // A fragments: a[g][kk] = E[m0+g*16+l][kk*32 + q*8 .. +7]
    bf16x8 a[4][4];
#pragma unroll
    for (int g = 0; g < 4; ++g) {
        const bf16x8* p = (const bf16x8*)(Eb + (size_t)(m0 + g * 16 + l) * D + q * 8);
#pragma unroll
        for (int kk = 0; kk < 4; ++kk) a[g][kk] = p[kk * 4];
    }

    // Row labels for the 16 output rows this lane owns (row = g*16 + q*4 + r).
    int lrow[16];
#pragma unroll
    for (int g = 0; g < 4; ++g)
#pragma unroll
        for (int r = 0; r < 4; ++r)
            lrow[g * 4 + r] = labels[m0 + g * 16 + q * 4 + r];

    float sum[16];
#pragma unroll
    for (int i = 0; i < 16; ++i) sum[i] = 0.0f;

#pragma clang loop unroll(disable)
    for (int t = 0; t < 16; ++t) {
        const int col = n_begin + t * 16 + l;
        const int lc = labels[col];
        const bf16x8* bp = (const bf16x8*)(Eb + (size_t)col * D + q * 8);
        bf16x8 b0 = bp[0], b1 = bp[4], b2 = bp[8], b3 = bp[12];

        f32x4 acc[4];
#pragma unroll
        for (int g = 0; g < 4; ++g) {
            acc[g] = (f32x4){0.f, 0.f, 0.f, 0.f};
            acc[g] = __builtin_amdgcn_mfma_f32_16x16x32_bf16(a[g][0], b0, acc[g], 0, 0, 0);
            acc[g] = __builtin_amdgcn_mfma_f32_16x16x32_bf16(a[g][1], b1, acc[g], 0, 0, 0);
            acc[g] = __builtin_amdgcn_mfma_f32_16x16x32_bf16(a[g][2], b2, acc[g], 0, 0, 0);
            acc[g] = __builtin_amdgcn_mfma_f32_16x16x32_bf16(a[g][3], b3, acc[g], 0, 0, 0);
        }

#pragma unroll
        for (int g = 0; g < 4; ++g) {
#pragma unroll
            for (int r = 0; r < 4; ++r) {
                float s = acc[g][r];
                bool eq = (lrow[g * 4 + r] == lc);
                float c = eq ? -LOG2E : LOG2E;
                float d = eq ? MLOG2E : -MLOG2E;
                sum[g * 4 + r] += EXP2(fmaf(s, c, d));
            }
        }
    }

    // Reduce across the 16 column-lanes (xor masks keep q fixed).
#pragma unroll
    for (int i = 0; i < 16; ++i) {
        float v = sum[i];
        v += __shfl_xor(v, 1);
        v += __shfl_xor(v, 2);
        v += __shfl_xor(v, 4);
        v += __shfl_xor(v, 8);
        sum[i] = v;
    }
    if (l == 0) {
#pragma unroll
        for (int g = 0; g < 4; ++g)
#pragma unroll
            for (int r = 0; r < 4; ++r)
                atomicAdd(&rowsum[m0 + g * 16 + q * 4 + r], sum[g * 4 + r]);
    }
}

// Kernel 3: out += sum_i log(rowsum[i]) / N, 32 blocks of 256.
__global__ void finalize_kernel(const float* __restrict__ rowsum, float* __restrict__ out) {
    __shared__ float red[4];
    int i = blockIdx.x * 256 + threadIdx.x;
    float v = LOG2(rowsum[i]) * LN2;
#pragma unroll
    for (int off = 1; off <= 32; off <<= 1) v += __shfl_xor(v, off);
    if ((threadIdx.x & 63) == 0) red[threadIdx.x >> 6] = v;
    __syncthreads();
    if (threadIdx.x == 0)
        atomicAdd(out, (red[0] + red[1] + red[2] + red[3]) * (1.0f / (float)N));
}

extern "C" void kernel_launch(void* const* d_in, const int* in_sizes, int n_in,
                              void* d_out, int out_size, void* d_ws, size_t ws_size,
                              hipStream_t stream) {
    const float* E = (const float*)d_in[0];
    const int* labels = (const int*)d_in[1];
    float* out = (float*)d_out;

    unsigned short* Eb = (unsigned short*)d_ws;                                     // 2 MiB
    float* rowsum = (float*)((char*)d_ws + (size_t)N * D * sizeof(unsigned short)); // 32 KiB

    prep_kernel<<<1024, 256, 0, stream>>>(E, Eb, rowsum, out);
    fused_kernel<<<1024, 256, 0, stream>>>(Eb, labels, rowsum);
    finalize_kernel<<<32, 256, 0, stream>>>(rowsum, out);
}

// Round 6
// 96.679 us; speedup vs baseline: 4.2631x; 1.1318x over previous
//
#include <hip/hip_runtime.h>
#include <hip/hip_bf16.h>

#define N 8192
#define D 128
#define LOG2E  1.44269504088896f
#define MLOG2E 0.14426950408890f   // MARGIN * log2e, MARGIN = 0.1
#define LN2    0.69314718055995f

#define COLSB   272                // padded bytes per staged column (256 + 16)
#define NSTEPS  8                  // 256 cols per block / 32 cols per step

typedef __attribute__((ext_vector_type(8))) short bf16x8;
typedef __attribute__((ext_vector_type(4))) float f32x4;

#if __has_builtin(__builtin_amdgcn_exp2f)
#define EXP2(x) __builtin_amdgcn_exp2f(x)
#else
#define EXP2(x) exp2f(x)
#endif
#if __has_builtin(__builtin_amdgcn_logf)
#define LOG2(x) __builtin_amdgcn_logf(x)
#else
#define LOG2(x) log2f(x)
#endif

static __device__ __forceinline__ unsigned short f2bf(float f) {
    union { float f; unsigned int u; } x;
    x.f = f;
    unsigned int r = ((x.u >> 16) & 1u) + 0x7FFFu;  // round-to-nearest-even
    return (unsigned short)((x.u + r) >> 16);
}

// Kernel 1: E (fp32) -> bf16 in ws; zero rowsum accumulator and out[0].
__global__ void prep_kernel(const float* __restrict__ E,
                            unsigned short* __restrict__ Eb,
                            float* __restrict__ rowsum,
                            float* __restrict__ out) {
    int idx = blockIdx.x * 256 + threadIdx.x;   // 262144 threads, 4 elems each
    float4 v = ((const float4*)E)[idx];
    ushort4 o;
    o.x = f2bf(v.x); o.y = f2bf(v.y); o.z = f2bf(v.z); o.w = f2bf(v.w);
    ((ushort4*)Eb)[idx] = o;
    if (idx < N) rowsum[idx] = 0.0f;
    if (idx == 0) out[0] = 0.0f;
}

// Kernel 2: fused sim = E*E^T -> exp(+/-(sim - margin)) -> row sums.
// R6 restructure: R1-R5 showed doubling resident waves does NOT help (R1
// 8 w/CU 48.7us vs R5 16 w/CU 54.8us) -> per-iter load->wait->compute
// serialization under memory queueing, not TLP shortage. Fix: block-shared
// B tile in LDS, double-buffered, global loads issued 2 steps ahead.
// Block = 256 rows x 256 cols (4 waves x 64 rows share one B tile: 4x fewer
// global B loads). 8 steps x 32 cols. LDS col stride 272B: balanced 8-cyc
// b128 reads (unpadded 256B is 2x bank-serialized).
// VGPR lessons: t-loop pinned rolled (R4: full unroll -> 216 VGPR);
// no min-waves launch_bounds (R2: spill); epilogue kept separate (R3).
__global__ __launch_bounds__(256) void fused_kernel(
        const unsigned short* __restrict__ Eb,
        const int* __restrict__ labels,
        float* __restrict__ rowsum) {
    __shared__ __align__(16) char ldsbuf[2][32 * COLSB];   // 17408 B

    const int tid  = threadIdx.x;
    const int wid  = tid >> 6;
    const int lane = tid & 63;
    const int cchunk = blockIdx.x & 31;    // 256-col span
    const int rgroup = blockIdx.x >> 5;    // 256-row span
    const int m0 = rgroup * 256 + wid * 64;
    const int n_begin = cchunk * 256;
    const int q = lane >> 4;       // 0..3
    const int l = lane & 15;       // 0..15

    // A fragments: a[g][kk] = E[m0+g*16+l][kk*32 + q*8 .. +7]
    bf16x8 a[4][4];
#pragma unroll
    for (int g = 0; g < 4; ++g) {
        const bf16x8* p = (const bf16x8*)(Eb + (size_t)(m0 + g * 16 + l) * D + q * 8);
#pragma unroll
        for (int kk = 0; kk < 4; ++kk) a[g][kk] = p[kk * 4];
    }

    // Row labels for the 16 output rows this lane owns (row = g*16 + q*4 + r).
    int lrow[16];
#pragma unroll
    for (int g = 0; g < 4; ++g)
#pragma unroll
        for (int r = 0; r < 4; ++r)
            lrow[g * 4 + r] = labels[m0 + g * 16 + q * 4 + r];

    float sum[16];
#pragma unroll
    for (int i = 0; i < 16; ++i) sum[i] = 0.0f;

    // ---- staging helpers: step tile = 32 cols x 256B = 8KB contiguous ----
    const char* gB = (const char*)Eb + (size_t)n_begin * 256;
    const int gofs = tid * 32;                          // 32B per thread
    const int lofs = (tid >> 3) * COLSB + (tid & 7) * 32;

    float4 v0, v1;
    {   // prologue: stage step 0, issue load of step 1
        const float4* p = (const float4*)(gB + gofs);
        v0 = p[0]; v1 = p[1];
        float4* dst = (float4*)(&ldsbuf[0][lofs]);
        dst[0] = v0; dst[1] = v1;
        const float4* p1 = (const float4*)(gB + 32 * 256 + gofs);
        v0 = p1[0]; v1 = p1[1];
    }
    __syncthreads();

#pragma clang loop unroll(disable)
    for (int t = 0; t < NSTEPS; ++t) {
        // write prefetched step t+1 into the other buffer (free: all waves
        // finished reading it at the barrier ending iter t-1)
        if (t + 1 < NSTEPS) {
            float4* dst = (float4*)(&ldsbuf[(t + 1) & 1][lofs]);
            dst[0] = v0; dst[1] = v1;
        }
        // issue global load of step t+2 (lands during compute below)
        if (t + 2 < NSTEPS) {
            const float4* p = (const float4*)(gB + (size_t)(t + 2) * 32 * 256 + gofs);
            v0 = p[0]; v1 = p[1];
        }

        // compute on buffer t&1: 2 subtiles of 16 cols
#pragma unroll
        for (int s = 0; s < 2; ++s) {
            const int col = n_begin + t * 32 + s * 16 + l;
            const int lc = labels[col];
            const char* lb = &ldsbuf[t & 1][(s * 16 + l) * COLSB + q * 16];
            bf16x8 b0 = *(const bf16x8*)(lb);
            bf16x8 b1 = *(const bf16x8*)(lb + 64);
            bf16x8 b2 = *(const bf16x8*)(lb + 128);
            bf16x8 b3 = *(const bf16x8*)(lb + 192);

            f32x4 acc[4];
#pragma unroll
            for (int g = 0; g < 4; ++g) {
                acc[g] = (f32x4){0.f, 0.f, 0.f, 0.f};
                acc[g] = __builtin_amdgcn_mfma_f32_16x16x32_bf16(a[g][0], b0, acc[g], 0, 0, 0);
                acc[g] = __builtin_amdgcn_mfma_f32_16x16x32_bf16(a[g][1], b1, acc[g], 0, 0, 0);
                acc[g] = __builtin_amdgcn_mfma_f32_16x16x32_bf16(a[g][2], b2, acc[g], 0, 0, 0);
                acc[g] = __builtin_amdgcn_mfma_f32_16x16x32_bf16(a[g][3], b3, acc[g], 0, 0, 0);
            }

#pragma unroll
            for (int g = 0; g < 4; ++g) {
#pragma unroll
                for (int r = 0; r < 4; ++r) {
                    float sv = acc[g][r];
                    bool eq = (lrow[g * 4 + r] == lc);
                    float c = eq ? -LOG2E : LOG2E;
                    float d = eq ? MLOG2E : -MLOG2E;
                    sum[g * 4 + r] += EXP2(fmaf(sv, c, d));
                }
            }
        }
        __syncthreads();
    }

    // Reduce across the 16 column-lanes (xor masks keep q fixed).
#pragma unroll
    for (int i = 0; i < 16; ++i) {
        float v = sum[i];
        v += __shfl_xor(v, 1);
        v += __shfl_xor(v, 2);
        v += __shfl_xor(v, 4);
        v += __shfl_xor(v, 8);
        sum[i] = v;
    }
    if (l == 0) {
#pragma unroll
        for (int g = 0; g < 4; ++g)
#pragma unroll
            for (int r = 0; r < 4; ++r)
                atomicAdd(&rowsum[m0 + g * 16 + q * 4 + r], sum[g * 4 + r]);
    }
}

// Kernel 3: out += sum_i log(rowsum[i]) / N, 32 blocks of 256.
__global__ void finalize_kernel(const float* __restrict__ rowsum, float* __restrict__ out) {
    __shared__ float red[4];
    int i = blockIdx.x * 256 + threadIdx.x;
    float v = LOG2(rowsum[i]) * LN2;
#pragma unroll
    for (int off = 1; off <= 32; off <<= 1) v += __shfl_xor(v, off);
    if ((threadIdx.x & 63) == 0) red[threadIdx.x >> 6] = v;
    __syncthreads();
    if (threadIdx.x == 0)
        atomicAdd(out, (red[0] + red[1] + red[2] + red[3]) * (1.0f / (float)N));
}

extern "C" void kernel_launch(void* const* d_in, const int* in_sizes, int n_in,
                              void* d_out, int out_size, void* d_ws, size_t ws_size,
                              hipStream_t stream) {
    const float* E = (const float*)d_in[0];
    const int* labels = (const int*)d_in[1];
    float* out = (float*)d_out;

    unsigned short* Eb = (unsigned short*)d_ws;                                     // 2 MiB
    float* rowsum = (float*)((char*)d_ws + (size_t)N * D * sizeof(unsigned short)); // 32 KiB

    prep_kernel<<<1024, 256, 0, stream>>>(E, Eb, rowsum, out);
    fused_kernel<<<1024, 256, 0, stream>>>(Eb, labels, rowsum);
    finalize_kernel<<<32, 256, 0, stream>>>(rowsum, out);
}